// Round 4
// baseline (1282.516 us; speedup 1.0000x reference)
//
#include <hip/hip_runtime.h>
#include <hip/hip_bf16.h>
#include <stdint.h>

typedef _Float16 f16x8 __attribute__((ext_vector_type(8)));
typedef float f32x4 __attribute__((ext_vector_type(4)));
typedef unsigned long long u64;
typedef unsigned int u32;

#define N_CODES 16384
#define N_VEC   16384

#define OUT_LOSS_OFF 4194304
#define OUT_IDX_OFF  4194305

// ws layout (bytes). High-water mark 17,565,712 B == rounds 1-2 proven extent.
// DO NOT grow past this: ws_size overflow corrupts adjacent harness buffers
// (round-3 failure: replay divergence from clobbered pristine-input copy).
#define WS_EHI   0u          // 8,388,608
#define WS_ELO   8388608u    // 8,388,608
#define WS_E2    16777216u   // 65,536
#define WS_SCR   16842752u   // u32 [8 splits][16384 rows] = 524,288
#define WS_FKEY  17367040u   // u64 [16384] = 131,072
#define WS_COUNT 17498112u   // 16
#define WS_LIST  17498128u   // 512 ints = 2,048
#define WS_FBIT  17500176u   // 16384 u32 = 65,536 -> ends 17,565,712

#define MARGIN 4.0e-3f
#define CAP 512

#define A_STRIDE 264                        // 256 + 8 pad (f16 units)
#define LDS_A_BYTES (128 * A_STRIDE * 2)    // 67584
#define LDS_BYTES (LDS_A_BYTES + 2048 * 4)  // + e2 stage = 75776 -> 2 blocks/CU

__device__ __forceinline__ u32 sortable_from_f32(float f) {
  u32 u = __float_as_uint(f);
  return (u & 0x80000000u) ? ~u : (u | 0x80000000u);
}
__device__ __forceinline__ float f32_from_sortable(u32 s) {
  u32 u = (s & 0x80000000u) ? (s & 0x7FFFFFFFu) : ~s;
  return __uint_as_float(u);
}

__device__ __forceinline__ void flag_row(int row, int* count, int* list, u32* fbit) {
  if (atomicExch(&fbit[row], 1u) == 0u) {
    const int p = atomicAdd(count, 1);
    if (p < CAP) list[p] = row;
  }
}

// ---------------- prep: embedding -> f16 hi/lo + exact ||e||^2 ----------------
__global__ __launch_bounds__(256) void k_prep(const float* __restrict__ emb,
                                              _Float16* __restrict__ ehi,
                                              _Float16* __restrict__ elo,
                                              float* __restrict__ e2) {
  const int code = blockIdx.x * 4 + (threadIdx.x >> 6);
  const int lane = threadIdx.x & 63;
  const float4 v = ((const float4*)emb)[code * 64 + lane];
  union { _Float16 f[4]; uint2 u2; } ph, pl;
  float vv[4] = {v.x, v.y, v.z, v.w};
  double s = 0.0;
#pragma unroll
  for (int j = 0; j < 4; ++j) {
    _Float16 h = (_Float16)vv[j];
    _Float16 l = (_Float16)(vv[j] - (float)h);
    ph.f[j] = h; pl.f[j] = l;
    s += (double)vv[j] * (double)vv[j];
  }
  ((uint2*)ehi)[code * 64 + lane] = ph.u2;
  ((uint2*)elo)[code * 64 + lane] = pl.u2;
#pragma unroll
  for (int off = 32; off; off >>= 1) s += __shfl_down(s, off);
  if (lane == 0) e2[code] = (float)s;
}

// ---------------- main fused GEMM + per-split argmin/top2 ----------------
// grid 1024: split = blockIdx & 7 (2048 codes), row tile = blockIdx >> 3 (128 rows).
// split == blockIdx % 8 aligns splits with the round-robin block->XCD mapping so each
// XCD's L2 holds only its own 2 MB of ehi/elo (speed heuristic; correctness is
// mapping-independent). A-hi in regs, A-lo resident in LDS, B direct global->VGPR
// double-buffered, no in-loop barriers. Results: per-split u32 score (gap detect)
// + u64 atomicMin on fkey (global argmin, first-occurrence tie-break via idx bits).
__global__ __launch_bounds__(256, 2) void k_gemm(const float* __restrict__ z,
                                                 const _Float16* __restrict__ ehi,
                                                 const _Float16* __restrict__ elo,
                                                 const float* __restrict__ e2,
                                                 u32* __restrict__ scr,
                                                 u64* __restrict__ fkey,
                                                 int* __restrict__ count,
                                                 int* __restrict__ list,
                                                 u32* __restrict__ fbit) {
  extern __shared__ char smem_raw[];
  _Float16* Asm = (_Float16*)smem_raw;
  float* e2s = (float*)(smem_raw + LDS_A_BYTES);

  const int tid = threadIdx.x;
  const int split = blockIdx.x & 7;
  const int rt = blockIdx.x >> 3;
  const int row0 = rt * 128;
  const int bb = row0 >> 10, hw0 = row0 & 1023;
  const int cb0 = split * 2048;

  const float4* z4 = (const float4*)z;

  // ---- stage e2 slice for this split (8 KB) ----
  {
    const float4* e24 = (const float4*)(e2 + cb0);
#pragma unroll
    for (int j = 0; j < 2; ++j)
      ((float4*)e2s)[tid + j * 256] = e24[tid + j * 256];
  }

  // ---- phase 1: stage A-hi tile (128 rows x 256 dims), NCHW transpose ----
  {
    const int fq = tid & 31, cg = tid >> 5;
    for (int i = 0; i < 32; ++i) {
      const int c = i * 8 + cg;
      float4 v = z4[(bb * 256 + c) * 256 + (hw0 >> 2) + fq];
      float vv[4] = {v.x, v.y, v.z, v.w};
      const int r = fq * 4;
#pragma unroll
      for (int j = 0; j < 4; ++j)
        Asm[(r + j) * A_STRIDE + c] = (_Float16)vv[j];
    }
  }
  __syncthreads();

  const int lane = tid & 63, w = tid >> 6;
  const int fr = lane & 15, q = lane >> 4;
  const int rbase = w * 32;

  // A-hi fragments -> registers (2 row-frags x 8 k-steps)
  f16x8 ah[2][8];
#pragma unroll
  for (int mf = 0; mf < 2; ++mf)
#pragma unroll
    for (int kc = 0; kc < 8; ++kc)
      ah[mf][kc] = *(const f16x8*)&Asm[(rbase + mf * 16 + fr) * A_STRIDE + kc * 32 + q * 8];
  __syncthreads();

  // ---- phase 2: stage A-lo into same LDS (stays resident for the sweep) ----
  {
    const int fq = tid & 31, cg = tid >> 5;
    for (int i = 0; i < 32; ++i) {
      const int c = i * 8 + cg;
      float4 v = z4[(bb * 256 + c) * 256 + (hw0 >> 2) + fq];
      float vv[4] = {v.x, v.y, v.z, v.w};
      const int r = fq * 4;
#pragma unroll
      for (int j = 0; j < 4; ++j) {
        float f = vv[j];
        _Float16 h = (_Float16)f;
        Asm[(r + j) * A_STRIDE + c] = (_Float16)(f - (float)h);
      }
    }
  }
  __syncthreads();

  // ---- code sweep: 64 tiles of 32 codes, K=256 in 8 steps of 32 ----
  u32 o0 = (u32)(cb0 + fr) * 512u + (u32)q * 16u;  // byte offset, nf=0 frag
  u32 o1 = o0 + 8192u;                              // nf=1 (+16 codes * 512 B)

  const char* EH = (const char*)ehi;
  const char* EL = (const char*)elo;

#define LDB(base, off, kcc) (*(const f16x8*)((base) + (off) + (kcc) * 64))

  f16x8 bh[2][2], bl[2][2];
  bh[0][0] = LDB(EH, o0, 0); bh[0][1] = LDB(EH, o1, 0);
  bl[0][0] = LDB(EL, o0, 0); bl[0][1] = LDB(EL, o1, 0);

  f32x4 acc[2][2] = {};
  u64 k1[2][4], k2[2][4];
#pragma unroll
  for (int mf = 0; mf < 2; ++mf)
#pragma unroll
    for (int rg = 0; rg < 4; ++rg) { k1[mf][rg] = ~0ull; k2[mf][rg] = ~0ull; }

  const u32 lds_a0 = (u32)(rbase + fr) * A_STRIDE;
  const u32 lds_a1 = (u32)(rbase + 16 + fr) * A_STRIDE;

  for (int t = 0; t < 64; ++t) {
#pragma unroll
    for (int kc = 0; kc < 8; ++kc) {
      const int cur = kc & 1, nxt = cur ^ 1;
      if (kc == 7) { o0 += 16384u; o1 += 16384u; }   // next 32-code tile
      const int kn = (kc + 1) & 7;
      // prefetch next k-step (tail overrun stays inside ws -> harmless)
      bh[nxt][0] = LDB(EH, o0, kn); bh[nxt][1] = LDB(EH, o1, kn);
      bl[nxt][0] = LDB(EL, o0, kn); bl[nxt][1] = LDB(EL, o1, kn);

      const f16x8 al0 = *(const f16x8*)&Asm[lds_a0 + kc * 32 + q * 8];
      const f16x8 al1 = *(const f16x8*)&Asm[lds_a1 + kc * 32 + q * 8];

#pragma unroll
      for (int nf = 0; nf < 2; ++nf) {
        acc[0][nf] = __builtin_amdgcn_mfma_f32_16x16x32_f16(ah[0][kc], bh[cur][nf], acc[0][nf], 0, 0, 0);
        acc[0][nf] = __builtin_amdgcn_mfma_f32_16x16x32_f16(al0,       bh[cur][nf], acc[0][nf], 0, 0, 0);
        acc[0][nf] = __builtin_amdgcn_mfma_f32_16x16x32_f16(ah[0][kc], bl[cur][nf], acc[0][nf], 0, 0, 0);
        acc[1][nf] = __builtin_amdgcn_mfma_f32_16x16x32_f16(ah[1][kc], bh[cur][nf], acc[1][nf], 0, 0, 0);
        acc[1][nf] = __builtin_amdgcn_mfma_f32_16x16x32_f16(al1,       bh[cur][nf], acc[1][nf], 0, 0, 0);
        acc[1][nf] = __builtin_amdgcn_mfma_f32_16x16x32_f16(ah[1][kc], bl[cur][nf], acc[1][nf], 0, 0, 0);
      }
    }

    // epilogue: score = ||e||^2 - 2*dot ; per-lane top-2 keys (e2 from LDS)
    const int cb = cb0 + t * 32;
#pragma unroll
    for (int nf = 0; nf < 2; ++nf) {
      const int gcode = cb + nf * 16 + fr;
      const float ev = e2s[t * 32 + nf * 16 + fr];
#pragma unroll
      for (int mf = 0; mf < 2; ++mf) {
#pragma unroll
        for (int rg = 0; rg < 4; ++rg) {
          const float sc = ev - 2.0f * acc[mf][nf][rg];
          const u64 key = ((u64)sortable_from_f32(sc) << 32) | (u32)gcode;
          const u64 old1 = k1[mf][rg];
          const bool lt = key < old1;
          k1[mf][rg] = lt ? key : old1;
          const u64 cand2 = lt ? old1 : key;
          const u64 old2 = k2[mf][rg];
          k2[mf][rg] = cand2 < old2 ? cand2 : old2;
        }
      }
    }
#pragma unroll
    for (int mf = 0; mf < 2; ++mf)
#pragma unroll
      for (int nf = 0; nf < 2; ++nf) acc[mf][nf] = (f32x4){0.0f, 0.0f, 0.0f, 0.0f};
  }

  // ---- reduce top-2 across the 16 column-lanes; publish per-split results ----
#pragma unroll
  for (int mf = 0; mf < 2; ++mf) {
#pragma unroll
    for (int rg = 0; rg < 4; ++rg) {
      u64 a1 = k1[mf][rg], a2 = k2[mf][rg];
#pragma unroll
      for (int off = 1; off < 16; off <<= 1) {
        u64 b1 = __shfl_xor(a1, off);
        u64 b2 = __shfl_xor(a2, off);
        u64 n1 = a1 < b1 ? a1 : b1;
        u64 mx = a1 < b1 ? b1 : a1;
        u64 mn2 = a2 < b2 ? a2 : b2;
        a1 = n1;
        a2 = mx < mn2 ? mx : mn2;
      }
      if (fr == 0) {
        const int row = row0 + rbase + mf * 16 + q * 4 + rg;
        scr[split * N_VEC + row] = (u32)(a1 >> 32);
        atomicMin(&fkey[row], a1);
        const float s1 = f32_from_sortable((u32)(a1 >> 32));
        const float s2 = f32_from_sortable((u32)(a2 >> 32));
        if (s2 - s1 < MARGIN) flag_row(row, count, list, fbit);
      }
    }
  }
}

// ---------------- merge: flag cross-split near-ties (fkey already = global min) ----------------
__global__ __launch_bounds__(256) void k_merge(const u32* __restrict__ scr,
                                               u64* __restrict__ fkey,
                                               int* __restrict__ count,
                                               int* __restrict__ list,
                                               u32* __restrict__ fbit) {
  const int r = blockIdx.x * 256 + threadIdx.x;
  u32 s1u = 0xFFFFFFFFu, s2u = 0xFFFFFFFFu;
#pragma unroll
  for (int s = 0; s < 8; ++s) {
    const u32 v = scr[s * N_VEC + r];
    const bool lt = v < s1u;
    const u32 c2 = lt ? s1u : v;
    s1u = lt ? v : s1u;
    s2u = c2 < s2u ? c2 : s2u;
  }
  const float s1 = f32_from_sortable(s1u);
  const float s2 = f32_from_sortable(s2u);
  if ((s2 - s1 < MARGIN) || (fbit[r] != 0u)) {
    fkey[r] = ~0ull;           // rescue rebuilds this row exactly
    flag_row(r, count, list, fbit);
  }
  // else: fkey[r] already holds the global min key from k_gemm's atomicMin
}

// ---------------- exact fp64 rescue for flagged rows ----------------
// grid CAP*32: blockIdx>>5 = list slot, blockIdx&31 = code chunk (512 codes)
__global__ __launch_bounds__(256) void k_rescue(const float* __restrict__ z,
                                                const float* __restrict__ emb,
                                                const int* __restrict__ count,
                                                const int* __restrict__ list,
                                                u64* __restrict__ fkey) {
  const int li = blockIdx.x >> 5;
  const int chunk = blockIdx.x & 31;
  int cnt = *count; if (cnt > CAP) cnt = CAP;
  if (li >= cnt) return;
  const int row = list[li];
  __shared__ float zl[256];
  const int b = row >> 10, hw = row & 1023;
  zl[threadIdx.x] = z[(b * 256 + threadIdx.x) * 1024 + hw];
  __syncthreads();
  const int lane = threadIdx.x & 63, wvi = threadIdx.x >> 6;
  const int c0 = lane * 4;
  const float z0 = zl[c0], z1 = zl[c0 + 1], z2 = zl[c0 + 2], z3 = zl[c0 + 3];
  u64 local = ~0ull;
  for (int it = 0; it < 128; ++it) {
    const int code = chunk * 512 + wvi * 128 + it;
    const float4 e4 = ((const float4*)emb)[code * 64 + lane];
    double dz = (double)e4.x * z0 + (double)e4.y * z1 + (double)e4.z * z2 + (double)e4.w * z3;
    double de = (double)e4.x * e4.x + (double)e4.y * e4.y + (double)e4.z * e4.z + (double)e4.w * e4.w;
#pragma unroll
    for (int off = 32; off; off >>= 1) { dz += __shfl_down(dz, off); de += __shfl_down(de, off); }
    if (lane == 0) {
      const double sc = de - 2.0 * dz;
      long long qv = (long long)((sc + 1024.0) * 8589934592.0);   // 2^33 fixed point
      if (qv < 0) qv = 0;
      const u64 key = ((u64)qv << 14) | (u32)code;
      if (key < local) local = key;
    }
  }
  if (lane == 0) atomicMin(fkey + row, local);
}

// ---------------- output: z_q (straight-through), loss, indices ----------------
__global__ __launch_bounds__(256) void k_out(const float* __restrict__ z,
                                             const float* __restrict__ emb,
                                             const u64* __restrict__ fkey,
                                             float* __restrict__ out) {
  const int gid = blockIdx.x * 256 + threadIdx.x;   // float4 units
  const int f0 = gid * 4;
  const int bc = f0 >> 10;
  const int hw = f0 & 1023;
  const int c = bc & 255, b = bc >> 8;
  const int n = b * 1024 + hw;
  const float4 z4 = ((const float4*)z)[gid];
  float zz[4] = {z4.x, z4.y, z4.z, z4.w};
  float o[4];
#pragma unroll
  for (int j = 0; j < 4; ++j) {
    const int idx = (int)(fkey[n + j] & 0x3FFFull);
    const float ev = emb[idx * 256 + c];
    o[j] = zz[j] + (ev - zz[j]);
  }
  float4 ov = {o[0], o[1], o[2], o[3]};
  ((float4*)out)[gid] = ov;
  if (gid == 0) out[OUT_LOSS_OFF] = 0.0f;
  if (gid < N_VEC) out[OUT_IDX_OFF + gid] = (float)(u32)(fkey[gid] & 0x3FFFull);
}

extern "C" void kernel_launch(void* const* d_in, const int* in_sizes, int n_in,
                              void* d_out, int out_size, void* d_ws, size_t ws_size,
                              hipStream_t stream) {
  const float* z = (const float*)d_in[0];
  const float* emb = (const float*)d_in[1];
  float* out = (float*)d_out;
  char* ws = (char*)d_ws;

  _Float16* ehi = (_Float16*)(ws + WS_EHI);
  _Float16* elo = (_Float16*)(ws + WS_ELO);
  float* e2 = (float*)(ws + WS_E2);
  u32* scr = (u32*)(ws + WS_SCR);
  u64* fkey = (u64*)(ws + WS_FKEY);
  int* count = (int*)(ws + WS_COUNT);
  int* list = (int*)(ws + WS_LIST);
  u32* fbit = (u32*)(ws + WS_FBIT);

  hipFuncSetAttribute((const void*)k_gemm, hipFuncAttributeMaxDynamicSharedMemorySize,
                      LDS_BYTES);
  hipMemsetAsync(ws + WS_COUNT, 0, 16, stream);
  hipMemsetAsync(ws + WS_FBIT, 0, 65536, stream);
  hipMemsetAsync(ws + WS_FKEY, 0xFF, 131072, stream);   // fkey = ~0ull

  k_prep<<<4096, 256, 0, stream>>>(emb, ehi, elo, e2);
  k_gemm<<<1024, 256, LDS_BYTES, stream>>>(z, ehi, elo, e2, scr, fkey, count, list, fbit);
  k_merge<<<64, 256, 0, stream>>>(scr, fkey, count, list, fbit);
  k_rescue<<<CAP * 32, 256, 0, stream>>>(z, emb, count, list, fkey);
  k_out<<<4096, 256, 0, stream>>>(z, emb, fkey, out);
}

// Round 5
// 1214.957 us; speedup vs baseline: 1.0556x; 1.0556x over previous
//
#include <hip/hip_runtime.h>
#include <hip/hip_bf16.h>
#include <stdint.h>

typedef _Float16 f16x8 __attribute__((ext_vector_type(8)));
typedef float f32x4 __attribute__((ext_vector_type(4)));
typedef unsigned long long u64;
typedef unsigned int u32;

#define N_CODES 16384
#define N_VEC   16384

#define OUT_LOSS_OFF 4194304
#define OUT_IDX_OFF  4194305

// ws layout (bytes). High-water mark 17,565,712 B == rounds 1-2-4 proven extent.
// DO NOT grow past this: ws_size overflow corrupts adjacent harness buffers.
#define WS_EHI   0u          // 8,388,608
#define WS_ELO   8388608u    // 8,388,608
#define WS_E2    16777216u   // 65,536
#define WS_SCR   16842752u   // u32 [8 splits][16384 rows] = 524,288
#define WS_FKEY  17367040u   // u64 [16384] = 131,072
#define WS_COUNT 17498112u   // 16
#define WS_LIST  17498128u   // 512 ints = 2,048
#define WS_FBIT  17500176u   // 16384 u32 = 65,536 -> ends 17,565,712

#define MARGIN 4.0e-3f
#define CAP 512

#define A_STRIDE 264                        // 256 + 8 pad (f16 units)
#define LDS_A_BYTES (128 * A_STRIDE * 2)    // 67584
#define LDS_B_OFF   LDS_A_BYTES             // 32 codes hi (64 B/row) + 32 lo = 4096
#define LDS_E2_OFF  (LDS_A_BYTES + 4096)    // 71680
#define LDS_BYTES   (LDS_E2_OFF + 8192)     // 79872 -> 2 blocks/CU (159744 <= 163840)

__device__ __forceinline__ u32 sortable_from_f32(float f) {
  u32 u = __float_as_uint(f);
  return (u & 0x80000000u) ? ~u : (u | 0x80000000u);
}
__device__ __forceinline__ float f32_from_sortable(u32 s) {
  u32 u = (s & 0x80000000u) ? (s & 0x7FFFFFFFu) : ~s;
  return __uint_as_float(u);
}

__device__ __forceinline__ void flag_row(int row, int* count, int* list, u32* fbit) {
  if (atomicExch(&fbit[row], 1u) == 0u) {
    const int p = atomicAdd(count, 1);
    if (p < CAP) list[p] = row;
  }
}

// ---------------- prep: embedding -> f16 hi/lo + exact ||e||^2 ----------------
__global__ __launch_bounds__(256) void k_prep(const float* __restrict__ emb,
                                              _Float16* __restrict__ ehi,
                                              _Float16* __restrict__ elo,
                                              float* __restrict__ e2) {
  const int code = blockIdx.x * 4 + (threadIdx.x >> 6);
  const int lane = threadIdx.x & 63;
  const float4 v = ((const float4*)emb)[code * 64 + lane];
  union { _Float16 f[4]; uint2 u2; } ph, pl;
  float vv[4] = {v.x, v.y, v.z, v.w};
  double s = 0.0;
#pragma unroll
  for (int j = 0; j < 4; ++j) {
    _Float16 h = (_Float16)vv[j];
    _Float16 l = (_Float16)(vv[j] - (float)h);
    ph.f[j] = h; pl.f[j] = l;
    s += (double)vv[j] * (double)vv[j];
  }
  ((uint2*)ehi)[code * 64 + lane] = ph.u2;
  ((uint2*)elo)[code * 64 + lane] = pl.u2;
#pragma unroll
  for (int off = 32; off; off >>= 1) s += __shfl_down(s, off);
  if (lane == 0) e2[code] = (float)s;
}

// ---------------- main fused GEMM + per-split argmin/top2 ----------------
// grid 1024: split = blockIdx & 7 (2048 codes, XCD-pinned), row tile = blockIdx >> 3
// (128 rows). m97-style barrier-fenced K-loop: per step the block stages one
// 32-code x 32-k (hi+lo) B slice into LDS (4 KB, one uint4 per thread, prefetched
// one step ahead in regs), waves consume via ds_read_b128. A-hi in regs, A-lo
// resident in LDS. B loads shared block-wide (TA lines / L2 traffic / 4 vs r4).
__global__ __launch_bounds__(256, 2) void k_gemm(const float* __restrict__ z,
                                                 const _Float16* __restrict__ ehi,
                                                 const _Float16* __restrict__ elo,
                                                 const float* __restrict__ e2,
                                                 u32* __restrict__ scr,
                                                 u64* __restrict__ fkey,
                                                 int* __restrict__ count,
                                                 int* __restrict__ list,
                                                 u32* __restrict__ fbit) {
  extern __shared__ char smem_raw[];
  _Float16* Asm = (_Float16*)smem_raw;
  char* Bb = smem_raw + LDS_B_OFF;
  float* e2s = (float*)(smem_raw + LDS_E2_OFF);

  const int tid = threadIdx.x;
  const int split = blockIdx.x & 7;
  const int rt = blockIdx.x >> 3;
  const int row0 = rt * 128;
  const int bb = row0 >> 10, hw0 = row0 & 1023;
  const int cb0 = split * 2048;

  const float4* z4 = (const float4*)z;

  // ---- stage e2 slice for this split (8 KB) ----
  {
    const float4* e24 = (const float4*)(e2 + cb0);
#pragma unroll
    for (int j = 0; j < 2; ++j)
      ((float4*)e2s)[tid + j * 256] = e24[tid + j * 256];
  }

  // ---- phase 1: stage A-hi tile (128 rows x 256 dims), NCHW transpose ----
  {
    const int fq = tid & 31, cg = tid >> 5;
    for (int i = 0; i < 32; ++i) {
      const int c = i * 8 + cg;
      float4 v = z4[(bb * 256 + c) * 256 + (hw0 >> 2) + fq];
      float vv[4] = {v.x, v.y, v.z, v.w};
      const int r = fq * 4;
#pragma unroll
      for (int j = 0; j < 4; ++j)
        Asm[(r + j) * A_STRIDE + c] = (_Float16)vv[j];
    }
  }
  __syncthreads();

  const int lane = tid & 63, w = tid >> 6;
  const int fr = lane & 15, q = lane >> 4;
  const int rbase = w * 32;

  // A-hi fragments -> registers (2 row-frags x 8 k-steps)
  f16x8 ah[2][8];
#pragma unroll
  for (int mf = 0; mf < 2; ++mf)
#pragma unroll
    for (int kc = 0; kc < 8; ++kc)
      ah[mf][kc] = *(const f16x8*)&Asm[(rbase + mf * 16 + fr) * A_STRIDE + kc * 32 + q * 8];
  __syncthreads();

  // ---- phase 2: stage A-lo into same LDS (stays resident for the sweep) ----
  {
    const int fq = tid & 31, cg = tid >> 5;
    for (int i = 0; i < 32; ++i) {
      const int c = i * 8 + cg;
      float4 v = z4[(bb * 256 + c) * 256 + (hw0 >> 2) + fq];
      float vv[4] = {v.x, v.y, v.z, v.w};
      const int r = fq * 4;
#pragma unroll
      for (int j = 0; j < 4; ++j) {
        float f = vv[j];
        _Float16 h = (_Float16)f;
        Asm[(r + j) * A_STRIDE + c] = (_Float16)(f - (float)h);
      }
    }
  }
  // (first loop barrier makes A-lo visible before any B-tile write/read)

  // ---- B staging setup: thread -> one uint4 of the 4 KB step-tile ----
  // tid<128: hi rows 0..31; tid>=128: lo rows 0..31. 64 B per code-row.
  const int srow = (tid & 127) >> 2;
  const int sb = tid & 3;
  const uint4* SRC = (tid < 128) ? (const uint4*)ehi : (const uint4*)elo;
  const u32 gbase = (u32)(cb0 + srow) * 32u + (u32)sb;  // uint4 index; +t*1024 +kc*4

  uint4 p = SRC[gbase];  // step 0

  f32x4 acc[2][2] = {};
  u64 k1[2][4], k2[2][4];
#pragma unroll
  for (int mf = 0; mf < 2; ++mf)
#pragma unroll
    for (int rg = 0; rg < 4; ++rg) { k1[mf][rg] = ~0ull; k2[mf][rg] = ~0ull; }

  const u32 lds_a0 = (u32)(rbase + fr) * A_STRIDE;
  const u32 lds_a1 = (u32)(rbase + 16 + fr) * A_STRIDE;

  // ---- code sweep: 512 steps = 64 tiles of 32 codes x 8 k-chunks ----
  for (int s = 0; s < 512; ++s) {
    __syncthreads();                       // prior step's B reads complete
    ((uint4*)Bb)[tid] = p;                 // commit this step's B slice
    const int sn = s + 1;
    if (sn < 512)
      p = SRC[gbase + (u32)(sn >> 3) * 1024u + (u32)(sn & 7) * 4u];
    __syncthreads();                       // B slice visible

    const int kc = s & 7;
    const f16x8 bh0 = *(const f16x8*)(Bb + fr * 64 + q * 16);
    const f16x8 bh1 = *(const f16x8*)(Bb + 1024 + fr * 64 + q * 16);
    const f16x8 bl0 = *(const f16x8*)(Bb + 2048 + fr * 64 + q * 16);
    const f16x8 bl1 = *(const f16x8*)(Bb + 3072 + fr * 64 + q * 16);
    const f16x8 al0 = *(const f16x8*)&Asm[lds_a0 + kc * 32 + q * 8];
    const f16x8 al1 = *(const f16x8*)&Asm[lds_a1 + kc * 32 + q * 8];
    const f16x8 ah0 = ah[0][kc], ah1 = ah[1][kc];

    acc[0][0] = __builtin_amdgcn_mfma_f32_16x16x32_f16(ah0, bh0, acc[0][0], 0, 0, 0);
    acc[0][0] = __builtin_amdgcn_mfma_f32_16x16x32_f16(al0, bh0, acc[0][0], 0, 0, 0);
    acc[0][0] = __builtin_amdgcn_mfma_f32_16x16x32_f16(ah0, bl0, acc[0][0], 0, 0, 0);
    acc[0][1] = __builtin_amdgcn_mfma_f32_16x16x32_f16(ah0, bh1, acc[0][1], 0, 0, 0);
    acc[0][1] = __builtin_amdgcn_mfma_f32_16x16x32_f16(al0, bh1, acc[0][1], 0, 0, 0);
    acc[0][1] = __builtin_amdgcn_mfma_f32_16x16x32_f16(ah0, bl1, acc[0][1], 0, 0, 0);
    acc[1][0] = __builtin_amdgcn_mfma_f32_16x16x32_f16(ah1, bh0, acc[1][0], 0, 0, 0);
    acc[1][0] = __builtin_amdgcn_mfma_f32_16x16x32_f16(al1, bh0, acc[1][0], 0, 0, 0);
    acc[1][0] = __builtin_amdgcn_mfma_f32_16x16x32_f16(ah1, bl0, acc[1][0], 0, 0, 0);
    acc[1][1] = __builtin_amdgcn_mfma_f32_16x16x32_f16(ah1, bh1, acc[1][1], 0, 0, 0);
    acc[1][1] = __builtin_amdgcn_mfma_f32_16x16x32_f16(al1, bh1, acc[1][1], 0, 0, 0);
    acc[1][1] = __builtin_amdgcn_mfma_f32_16x16x32_f16(ah1, bl1, acc[1][1], 0, 0, 0);

    if (kc == 7) {
      const int t = s >> 3;
      const int cb = cb0 + t * 32;
#pragma unroll
      for (int nf = 0; nf < 2; ++nf) {
        const int gcode = cb + nf * 16 + fr;
        const float ev = e2s[t * 32 + nf * 16 + fr];
#pragma unroll
        for (int mf = 0; mf < 2; ++mf) {
#pragma unroll
          for (int rg = 0; rg < 4; ++rg) {
            const float sc = ev - 2.0f * acc[mf][nf][rg];
            const u64 key = ((u64)sortable_from_f32(sc) << 32) | (u32)gcode;
            const u64 old1 = k1[mf][rg];
            const bool lt = key < old1;
            k1[mf][rg] = lt ? key : old1;
            const u64 cand2 = lt ? old1 : key;
            const u64 old2 = k2[mf][rg];
            k2[mf][rg] = cand2 < old2 ? cand2 : old2;
          }
        }
      }
#pragma unroll
      for (int mf = 0; mf < 2; ++mf)
#pragma unroll
        for (int nf = 0; nf < 2; ++nf) acc[mf][nf] = (f32x4){0.0f, 0.0f, 0.0f, 0.0f};
    }
  }

  // ---- reduce top-2 across the 16 column-lanes; publish per-split results ----
#pragma unroll
  for (int mf = 0; mf < 2; ++mf) {
#pragma unroll
    for (int rg = 0; rg < 4; ++rg) {
      u64 a1 = k1[mf][rg], a2 = k2[mf][rg];
#pragma unroll
      for (int off = 1; off < 16; off <<= 1) {
        u64 b1 = __shfl_xor(a1, off);
        u64 b2 = __shfl_xor(a2, off);
        u64 n1 = a1 < b1 ? a1 : b1;
        u64 mx = a1 < b1 ? b1 : a1;
        u64 mn2 = a2 < b2 ? a2 : b2;
        a1 = n1;
        a2 = mx < mn2 ? mx : mn2;
      }
      if (fr == 0) {
        const int row = row0 + rbase + mf * 16 + q * 4 + rg;
        scr[split * N_VEC + row] = (u32)(a1 >> 32);
        atomicMin(&fkey[row], a1);
        const float s1 = f32_from_sortable((u32)(a1 >> 32));
        const float s2 = f32_from_sortable((u32)(a2 >> 32));
        if (s2 - s1 < MARGIN) flag_row(row, count, list, fbit);
      }
    }
  }
}

// ---------------- merge: flag cross-split near-ties (fkey already = global min) ----------------
__global__ __launch_bounds__(256) void k_merge(const u32* __restrict__ scr,
                                               u64* __restrict__ fkey,
                                               int* __restrict__ count,
                                               int* __restrict__ list,
                                               u32* __restrict__ fbit) {
  const int r = blockIdx.x * 256 + threadIdx.x;
  u32 s1u = 0xFFFFFFFFu, s2u = 0xFFFFFFFFu;
#pragma unroll
  for (int s = 0; s < 8; ++s) {
    const u32 v = scr[s * N_VEC + r];
    const bool lt = v < s1u;
    const u32 c2 = lt ? s1u : v;
    s1u = lt ? v : s1u;
    s2u = c2 < s2u ? c2 : s2u;
  }
  const float s1 = f32_from_sortable(s1u);
  const float s2 = f32_from_sortable(s2u);
  if ((s2 - s1 < MARGIN) || (fbit[r] != 0u)) {
    fkey[r] = ~0ull;           // rescue rebuilds this row exactly
    flag_row(r, count, list, fbit);
  }
}

// ---------------- exact fp64 rescue for flagged rows ----------------
__global__ __launch_bounds__(256) void k_rescue(const float* __restrict__ z,
                                                const float* __restrict__ emb,
                                                const int* __restrict__ count,
                                                const int* __restrict__ list,
                                                u64* __restrict__ fkey) {
  const int li = blockIdx.x >> 5;
  const int chunk = blockIdx.x & 31;
  int cnt = *count; if (cnt > CAP) cnt = CAP;
  if (li >= cnt) return;
  const int row = list[li];
  __shared__ float zl[256];
  const int b = row >> 10, hw = row & 1023;
  zl[threadIdx.x] = z[(b * 256 + threadIdx.x) * 1024 + hw];
  __syncthreads();
  const int lane = threadIdx.x & 63, wvi = threadIdx.x >> 6;
  const int c0 = lane * 4;
  const float z0 = zl[c0], z1 = zl[c0 + 1], z2 = zl[c0 + 2], z3 = zl[c0 + 3];
  u64 local = ~0ull;
  for (int it = 0; it < 128; ++it) {
    const int code = chunk * 512 + wvi * 128 + it;
    const float4 e4 = ((const float4*)emb)[code * 64 + lane];
    double dz = (double)e4.x * z0 + (double)e4.y * z1 + (double)e4.z * z2 + (double)e4.w * z3;
    double de = (double)e4.x * e4.x + (double)e4.y * e4.y + (double)e4.z * e4.z + (double)e4.w * e4.w;
#pragma unroll
    for (int off = 32; off; off >>= 1) { dz += __shfl_down(dz, off); de += __shfl_down(de, off); }
    if (lane == 0) {
      const double sc = de - 2.0 * dz;
      long long qv = (long long)((sc + 1024.0) * 8589934592.0);   // 2^33 fixed point
      if (qv < 0) qv = 0;
      const u64 key = ((u64)qv << 14) | (u32)code;
      if (key < local) local = key;
    }
  }
  if (lane == 0) atomicMin(fkey + row, local);
}

// ---------------- output: z_q (straight-through), loss, indices ----------------
__global__ __launch_bounds__(256) void k_out(const float* __restrict__ z,
                                             const float* __restrict__ emb,
                                             const u64* __restrict__ fkey,
                                             float* __restrict__ out) {
  const int gid = blockIdx.x * 256 + threadIdx.x;   // float4 units
  const int f0 = gid * 4;
  const int bc = f0 >> 10;
  const int hw = f0 & 1023;
  const int c = bc & 255, b = bc >> 8;
  const int n = b * 1024 + hw;
  const float4 z4 = ((const float4*)z)[gid];
  float zz[4] = {z4.x, z4.y, z4.z, z4.w};
  float o[4];
#pragma unroll
  for (int j = 0; j < 4; ++j) {
    const int idx = (int)(fkey[n + j] & 0x3FFFull);
    const float ev = emb[idx * 256 + c];
    o[j] = zz[j] + (ev - zz[j]);
  }
  float4 ov = {o[0], o[1], o[2], o[3]};
  ((float4*)out)[gid] = ov;
  if (gid == 0) out[OUT_LOSS_OFF] = 0.0f;
  if (gid < N_VEC) out[OUT_IDX_OFF + gid] = (float)(u32)(fkey[gid] & 0x3FFFull);
}

extern "C" void kernel_launch(void* const* d_in, const int* in_sizes, int n_in,
                              void* d_out, int out_size, void* d_ws, size_t ws_size,
                              hipStream_t stream) {
  const float* z = (const float*)d_in[0];
  const float* emb = (const float*)d_in[1];
  float* out = (float*)d_out;
  char* ws = (char*)d_ws;

  _Float16* ehi = (_Float16*)(ws + WS_EHI);
  _Float16* elo = (_Float16*)(ws + WS_ELO);
  float* e2 = (float*)(ws + WS_E2);
  u32* scr = (u32*)(ws + WS_SCR);
  u64* fkey = (u64*)(ws + WS_FKEY);
  int* count = (int*)(ws + WS_COUNT);
  int* list = (int*)(ws + WS_LIST);
  u32* fbit = (u32*)(ws + WS_FBIT);

  hipFuncSetAttribute((const void*)k_gemm, hipFuncAttributeMaxDynamicSharedMemorySize,
                      LDS_BYTES);
  hipMemsetAsync(ws + WS_COUNT, 0, 16, stream);
  hipMemsetAsync(ws + WS_FBIT, 0, 65536, stream);
  hipMemsetAsync(ws + WS_FKEY, 0xFF, 131072, stream);   // fkey = ~0ull

  k_prep<<<4096, 256, 0, stream>>>(emb, ehi, elo, e2);
  k_gemm<<<1024, 256, LDS_BYTES, stream>>>(z, ehi, elo, e2, scr, fkey, count, list, fbit);
  k_merge<<<64, 256, 0, stream>>>(scr, fkey, count, list, fbit);
  k_rescue<<<CAP * 32, 256, 0, stream>>>(z, emb, count, list, fkey);
  k_out<<<4096, 256, 0, stream>>>(z, emb, fkey, out);
}

// Round 6
// 755.320 us; speedup vs baseline: 1.6980x; 1.6085x over previous
//
#include <hip/hip_runtime.h>
#include <hip/hip_bf16.h>
#include <stdint.h>

typedef _Float16 f16x8 __attribute__((ext_vector_type(8)));
typedef float f32x4 __attribute__((ext_vector_type(4)));
typedef unsigned long long u64;
typedef unsigned int u32;

#define N_CODES 16384
#define N_VEC   16384

#define OUT_LOSS_OFF 4194304
#define OUT_IDX_OFF  4194305

// ws layout (bytes). High-water mark 17,565,712 B == rounds 1-2-4-5 proven extent.
// DO NOT grow past this: ws_size overflow corrupts adjacent harness buffers.
#define WS_EHI   0u          // 8,388,608
#define WS_ELO   8388608u    // 8,388,608
#define WS_E2    16777216u   // 65,536
#define WS_SCR   16842752u   // u32 [8 splits][16384 rows] = 524,288
#define WS_FKEY  17367040u   // u64 [16384] = 131,072
#define WS_COUNT 17498112u   // 16
#define WS_LIST  17498128u   // 512 ints = 2,048
#define WS_FBIT  17500176u   // 16384 u32 = 65,536 -> ends 17,565,712

#define MARGIN 4.0e-3f
#define CAP 512

#define A_STRIDE 264                        // 256 + 8 pad (f16 units)
#define LDS_A_BYTES (128 * A_STRIDE * 2)    // 67584 (one plane; staged hi then lo)
// After the A prologue the same LDS is reused: [0..4096) B step-slice, [4096..12288) e2s.
#define LDS_BYTES LDS_A_BYTES               // 67584 -> 2 blocks/CU

__device__ __forceinline__ u32 sortable_from_f32(float f) {
  u32 u = __float_as_uint(f);
  return (u & 0x80000000u) ? ~u : (u | 0x80000000u);
}
__device__ __forceinline__ float f32_from_sortable(u32 s) {
  u32 u = (s & 0x80000000u) ? (s & 0x7FFFFFFFu) : ~s;
  return __uint_as_float(u);
}

__device__ __forceinline__ void flag_row(int row, int* count, int* list, u32* fbit) {
  if (atomicExch(&fbit[row], 1u) == 0u) {
    const int p = atomicAdd(count, 1);
    if (p < CAP) list[p] = row;
  }
}

// ---------------- prep: embedding -> f16 hi/lo + exact ||e||^2 ----------------
__global__ __launch_bounds__(256) void k_prep(const float* __restrict__ emb,
                                              _Float16* __restrict__ ehi,
                                              _Float16* __restrict__ elo,
                                              float* __restrict__ e2) {
  const int code = blockIdx.x * 4 + (threadIdx.x >> 6);
  const int lane = threadIdx.x & 63;
  const float4 v = ((const float4*)emb)[code * 64 + lane];
  union { _Float16 f[4]; uint2 u2; } ph, pl;
  float vv[4] = {v.x, v.y, v.z, v.w};
  double s = 0.0;
#pragma unroll
  for (int j = 0; j < 4; ++j) {
    _Float16 h = (_Float16)vv[j];
    _Float16 l = (_Float16)(vv[j] - (float)h);
    ph.f[j] = h; pl.f[j] = l;
    s += (double)vv[j] * (double)vv[j];
  }
  ((uint2*)ehi)[code * 64 + lane] = ph.u2;
  ((uint2*)elo)[code * 64 + lane] = pl.u2;
#pragma unroll
  for (int off = 32; off; off >>= 1) s += __shfl_down(s, off);
  if (lane == 0) e2[code] = (float)s;
}

// ---------------- main fused GEMM + per-split argmin/top2 ----------------
// grid 1024: split = blockIdx & 7 (2048 codes, XCD-pinned), row tile = blockIdx >> 3
// (128 rows). Wave owns 32 rows; A-hi AND A-lo fragments in registers (statically
// indexed 2x8 arrays -- round-5 spill was caused by runtime kc indexing). Per kc-step
// the block stages one 32-code x 32-k (hi+lo) B slice (4 KB) into LDS, prefetched one
// step ahead in a register; waves consume via 4 ds_read_b128. MFMA-bound by design:
// per-CU step-round ~400 LDS-cyc < ~466 MFMA-cyc.
__global__ __launch_bounds__(256, 2) void k_gemm(const float* __restrict__ z,
                                                 const _Float16* __restrict__ ehi,
                                                 const _Float16* __restrict__ elo,
                                                 const float* __restrict__ e2,
                                                 u32* __restrict__ scr,
                                                 u64* __restrict__ fkey,
                                                 int* __restrict__ count,
                                                 int* __restrict__ list,
                                                 u32* __restrict__ fbit) {
  extern __shared__ char smem_raw[];
  _Float16* Asm = (_Float16*)smem_raw;
  char* Bb = smem_raw;                       // overlays A region after prologue
  float* e2s = (float*)(smem_raw + 4096);    // 8 KB, after B slice

  const int tid = threadIdx.x;
  const int split = blockIdx.x & 7;
  const int rt = blockIdx.x >> 3;
  const int row0 = rt * 128;
  const int bb = row0 >> 10, hw0 = row0 & 1023;
  const int cb0 = split * 2048;

  const float4* z4 = (const float4*)z;
  const int lane = tid & 63, w = tid >> 6;
  const int fr = lane & 15, q = lane >> 4;
  const int rbase = w * 32;

  f16x8 ah[2][8], al[2][8];

  // ---- phase 1: stage A-hi tile (128 rows x 256 dims), NCHW transpose ----
  {
    const int fq = tid & 31, cg = tid >> 5;
    for (int i = 0; i < 32; ++i) {
      const int c = i * 8 + cg;
      float4 v = z4[(bb * 256 + c) * 256 + (hw0 >> 2) + fq];
      float vv[4] = {v.x, v.y, v.z, v.w};
      const int r = fq * 4;
#pragma unroll
      for (int j = 0; j < 4; ++j)
        Asm[(r + j) * A_STRIDE + c] = (_Float16)vv[j];
    }
  }
  __syncthreads();
#pragma unroll
  for (int mf = 0; mf < 2; ++mf)
#pragma unroll
    for (int kc = 0; kc < 8; ++kc)
      ah[mf][kc] = *(const f16x8*)&Asm[(rbase + mf * 16 + fr) * A_STRIDE + kc * 32 + q * 8];
  __syncthreads();

  // ---- phase 2: stage A-lo into same buffer, load fragments ----
  {
    const int fq = tid & 31, cg = tid >> 5;
    for (int i = 0; i < 32; ++i) {
      const int c = i * 8 + cg;
      float4 v = z4[(bb * 256 + c) * 256 + (hw0 >> 2) + fq];
      float vv[4] = {v.x, v.y, v.z, v.w};
      const int r = fq * 4;
#pragma unroll
      for (int j = 0; j < 4; ++j) {
        float f = vv[j];
        _Float16 h = (_Float16)f;
        Asm[(r + j) * A_STRIDE + c] = (_Float16)(f - (float)h);
      }
    }
  }
  __syncthreads();
#pragma unroll
  for (int mf = 0; mf < 2; ++mf)
#pragma unroll
    for (int kc = 0; kc < 8; ++kc)
      al[mf][kc] = *(const f16x8*)&Asm[(rbase + mf * 16 + fr) * A_STRIDE + kc * 32 + q * 8];
  __syncthreads();   // al reads done before B/e2 overlay writes

  // ---- stage e2 slice for this split (8 KB at smem+4096) ----
  {
    const float4* e24 = (const float4*)(e2 + cb0);
#pragma unroll
    for (int j = 0; j < 2; ++j)
      ((float4*)e2s)[tid + j * 256] = e24[tid + j * 256];
  }

  // ---- B staging setup: thread -> one uint4 of the 4 KB step-slice ----
  // tid<128: hi rows 0..31; tid>=128: lo rows 0..31. 64 B per code-row per kc.
  const int srow = (tid & 127) >> 2;
  const int sb = tid & 3;
  const uint4* SRC = (tid < 128) ? (const uint4*)ehi : (const uint4*)elo;
  const u32 gbase = (u32)(cb0 + srow) * 32u + (u32)sb;  // uint4 idx; +t*1024 +kc*4

  uint4 p = SRC[gbase];  // step (t=0, kc=0)

  f32x4 acc[2][2] = {};
  u64 k1[2][4], k2[2][4];
#pragma unroll
  for (int mf = 0; mf < 2; ++mf)
#pragma unroll
    for (int rg = 0; rg < 4; ++rg) { k1[mf][rg] = ~0ull; k2[mf][rg] = ~0ull; }

  // ---- code sweep: 64 tiles of 32 codes, K=256 as 8 statically-unrolled kc-steps ----
  for (int t = 0; t < 64; ++t) {
#pragma unroll
    for (int kc = 0; kc < 8; ++kc) {
      __syncthreads();                       // prior step's B reads complete
      ((uint4*)Bb)[tid] = p;                 // commit this step's B slice
      const int sn = t * 8 + kc + 1;
      if (sn < 512)
        p = SRC[gbase + (u32)(sn >> 3) * 1024u + (u32)(sn & 7) * 4u];
      __syncthreads();                       // B slice visible

      const f16x8 bh0 = *(const f16x8*)(Bb + fr * 64 + q * 16);
      const f16x8 bh1 = *(const f16x8*)(Bb + 1024 + fr * 64 + q * 16);
      const f16x8 bl0 = *(const f16x8*)(Bb + 2048 + fr * 64 + q * 16);
      const f16x8 bl1 = *(const f16x8*)(Bb + 3072 + fr * 64 + q * 16);
      const f16x8 ah0 = ah[0][kc], ah1 = ah[1][kc];
      const f16x8 al0 = al[0][kc], al1 = al[1][kc];

      acc[0][0] = __builtin_amdgcn_mfma_f32_16x16x32_f16(ah0, bh0, acc[0][0], 0, 0, 0);
      acc[0][0] = __builtin_amdgcn_mfma_f32_16x16x32_f16(al0, bh0, acc[0][0], 0, 0, 0);
      acc[0][0] = __builtin_amdgcn_mfma_f32_16x16x32_f16(ah0, bl0, acc[0][0], 0, 0, 0);
      acc[0][1] = __builtin_amdgcn_mfma_f32_16x16x32_f16(ah0, bh1, acc[0][1], 0, 0, 0);
      acc[0][1] = __builtin_amdgcn_mfma_f32_16x16x32_f16(al0, bh1, acc[0][1], 0, 0, 0);
      acc[0][1] = __builtin_amdgcn_mfma_f32_16x16x32_f16(ah0, bl1, acc[0][1], 0, 0, 0);
      acc[1][0] = __builtin_amdgcn_mfma_f32_16x16x32_f16(ah1, bh0, acc[1][0], 0, 0, 0);
      acc[1][0] = __builtin_amdgcn_mfma_f32_16x16x32_f16(al1, bh0, acc[1][0], 0, 0, 0);
      acc[1][0] = __builtin_amdgcn_mfma_f32_16x16x32_f16(ah1, bl0, acc[1][0], 0, 0, 0);
      acc[1][1] = __builtin_amdgcn_mfma_f32_16x16x32_f16(ah1, bh1, acc[1][1], 0, 0, 0);
      acc[1][1] = __builtin_amdgcn_mfma_f32_16x16x32_f16(al1, bh1, acc[1][1], 0, 0, 0);
      acc[1][1] = __builtin_amdgcn_mfma_f32_16x16x32_f16(ah1, bl1, acc[1][1], 0, 0, 0);
    }

    // epilogue: score = ||e||^2 - 2*dot ; per-lane top-2 keys (e2 from LDS)
    const int cb = cb0 + t * 32;
#pragma unroll
    for (int nf = 0; nf < 2; ++nf) {
      const int gcode = cb + nf * 16 + fr;
      const float ev = e2s[t * 32 + nf * 16 + fr];
#pragma unroll
      for (int mf = 0; mf < 2; ++mf) {
#pragma unroll
        for (int rg = 0; rg < 4; ++rg) {
          const float sc = ev - 2.0f * acc[mf][nf][rg];
          const u64 key = ((u64)sortable_from_f32(sc) << 32) | (u32)gcode;
          const u64 old1 = k1[mf][rg];
          const bool lt = key < old1;
          k1[mf][rg] = lt ? key : old1;
          const u64 cand2 = lt ? old1 : key;
          const u64 old2 = k2[mf][rg];
          k2[mf][rg] = cand2 < old2 ? cand2 : old2;
        }
      }
    }
#pragma unroll
    for (int mf = 0; mf < 2; ++mf)
#pragma unroll
      for (int nf = 0; nf < 2; ++nf) acc[mf][nf] = (f32x4){0.0f, 0.0f, 0.0f, 0.0f};
  }

  // ---- reduce top-2 across the 16 column-lanes; publish per-split results ----
#pragma unroll
  for (int mf = 0; mf < 2; ++mf) {
#pragma unroll
    for (int rg = 0; rg < 4; ++rg) {
      u64 a1 = k1[mf][rg], a2 = k2[mf][rg];
#pragma unroll
      for (int off = 1; off < 16; off <<= 1) {
        u64 b1 = __shfl_xor(a1, off);
        u64 b2 = __shfl_xor(a2, off);
        u64 n1 = a1 < b1 ? a1 : b1;
        u64 mx = a1 < b1 ? b1 : a1;
        u64 mn2 = a2 < b2 ? a2 : b2;
        a1 = n1;
        a2 = mx < mn2 ? mx : mn2;
      }
      if (fr == 0) {
        const int row = row0 + rbase + mf * 16 + q * 4 + rg;
        scr[split * N_VEC + row] = (u32)(a1 >> 32);
        atomicMin(&fkey[row], a1);
        const float s1 = f32_from_sortable((u32)(a1 >> 32));
        const float s2 = f32_from_sortable((u32)(a2 >> 32));
        if (s2 - s1 < MARGIN) flag_row(row, count, list, fbit);
      }
    }
  }
}

// ---------------- merge: flag cross-split near-ties (fkey already = global min) ----------------
__global__ __launch_bounds__(256) void k_merge(const u32* __restrict__ scr,
                                               u64* __restrict__ fkey,
                                               int* __restrict__ count,
                                               int* __restrict__ list,
                                               u32* __restrict__ fbit) {
  const int r = blockIdx.x * 256 + threadIdx.x;
  u32 s1u = 0xFFFFFFFFu, s2u = 0xFFFFFFFFu;
#pragma unroll
  for (int s = 0; s < 8; ++s) {
    const u32 v = scr[s * N_VEC + r];
    const bool lt = v < s1u;
    const u32 c2 = lt ? s1u : v;
    s1u = lt ? v : s1u;
    s2u = c2 < s2u ? c2 : s2u;
  }
  const float s1 = f32_from_sortable(s1u);
  const float s2 = f32_from_sortable(s2u);
  if ((s2 - s1 < MARGIN) || (fbit[r] != 0u)) {
    fkey[r] = ~0ull;           // rescue rebuilds this row exactly
    flag_row(r, count, list, fbit);
  }
}

// ---------------- exact fp64 rescue for flagged rows ----------------
__global__ __launch_bounds__(256) void k_rescue(const float* __restrict__ z,
                                                const float* __restrict__ emb,
                                                const int* __restrict__ count,
                                                const int* __restrict__ list,
                                                u64* __restrict__ fkey) {
  const int li = blockIdx.x >> 5;
  const int chunk = blockIdx.x & 31;
  int cnt = *count; if (cnt > CAP) cnt = CAP;
  if (li >= cnt) return;
  const int row = list[li];
  __shared__ float zl[256];
  const int b = row >> 10, hw = row & 1023;
  zl[threadIdx.x] = z[(b * 256 + threadIdx.x) * 1024 + hw];
  __syncthreads();
  const int lane = threadIdx.x & 63, wvi = threadIdx.x >> 6;
  const int c0 = lane * 4;
  const float z0 = zl[c0], z1 = zl[c0 + 1], z2 = zl[c0 + 2], z3 = zl[c0 + 3];
  u64 local = ~0ull;
  for (int it = 0; it < 128; ++it) {
    const int code = chunk * 512 + wvi * 128 + it;
    const float4 e4 = ((const float4*)emb)[code * 64 + lane];
    double dz = (double)e4.x * z0 + (double)e4.y * z1 + (double)e4.z * z2 + (double)e4.w * z3;
    double de = (double)e4.x * e4.x + (double)e4.y * e4.y + (double)e4.z * e4.z + (double)e4.w * e4.w;
#pragma unroll
    for (int off = 32; off; off >>= 1) { dz += __shfl_down(dz, off); de += __shfl_down(de, off); }
    if (lane == 0) {
      const double sc = de - 2.0 * dz;
      long long qv = (long long)((sc + 1024.0) * 8589934592.0);   // 2^33 fixed point
      if (qv < 0) qv = 0;
      const u64 key = ((u64)qv << 14) | (u32)code;
      if (key < local) local = key;
    }
  }
  if (lane == 0) atomicMin(fkey + row, local);
}

// ---------------- output: z_q (straight-through), loss, indices ----------------
__global__ __launch_bounds__(256) void k_out(const float* __restrict__ z,
                                             const float* __restrict__ emb,
                                             const u64* __restrict__ fkey,
                                             float* __restrict__ out) {
  const int gid = blockIdx.x * 256 + threadIdx.x;   // float4 units
  const int f0 = gid * 4;
  const int bc = f0 >> 10;
  const int hw = f0 & 1023;
  const int c = bc & 255, b = bc >> 8;
  const int n = b * 1024 + hw;
  const float4 z4 = ((const float4*)z)[gid];
  float zz[4] = {z4.x, z4.y, z4.z, z4.w};
  float o[4];
#pragma unroll
  for (int j = 0; j < 4; ++j) {
    const int idx = (int)(fkey[n + j] & 0x3FFFull);
    const float ev = emb[idx * 256 + c];
    o[j] = zz[j] + (ev - zz[j]);
  }
  float4 ov = {o[0], o[1], o[2], o[3]};
  ((float4*)out)[gid] = ov;
  if (gid == 0) out[OUT_LOSS_OFF] = 0.0f;
  if (gid < N_VEC) out[OUT_IDX_OFF + gid] = (float)(u32)(fkey[gid] & 0x3FFFull);
}

extern "C" void kernel_launch(void* const* d_in, const int* in_sizes, int n_in,
                              void* d_out, int out_size, void* d_ws, size_t ws_size,
                              hipStream_t stream) {
  const float* z = (const float*)d_in[0];
  const float* emb = (const float*)d_in[1];
  float* out = (float*)d_out;
  char* ws = (char*)d_ws;

  _Float16* ehi = (_Float16*)(ws + WS_EHI);
  _Float16* elo = (_Float16*)(ws + WS_ELO);
  float* e2 = (float*)(ws + WS_E2);
  u32* scr = (u32*)(ws + WS_SCR);
  u64* fkey = (u64*)(ws + WS_FKEY);
  int* count = (int*)(ws + WS_COUNT);
  int* list = (int*)(ws + WS_LIST);
  u32* fbit = (u32*)(ws + WS_FBIT);

  hipFuncSetAttribute((const void*)k_gemm, hipFuncAttributeMaxDynamicSharedMemorySize,
                      LDS_BYTES);
  hipMemsetAsync(ws + WS_COUNT, 0, 16, stream);
  hipMemsetAsync(ws + WS_FBIT, 0, 65536, stream);
  hipMemsetAsync(ws + WS_FKEY, 0xFF, 131072, stream);   // fkey = ~0ull

  k_prep<<<4096, 256, 0, stream>>>(emb, ehi, elo, e2);
  k_gemm<<<1024, 256, LDS_BYTES, stream>>>(z, ehi, elo, e2, scr, fkey, count, list, fbit);
  k_merge<<<64, 256, 0, stream>>>(scr, fkey, count, list, fbit);
  k_rescue<<<CAP * 32, 256, 0, stream>>>(z, emb, count, list, fkey);
  k_out<<<4096, 256, 0, stream>>>(z, emb, fkey, out);
}